// Round 2
// baseline (309.909 us; speedup 1.0000x reference)
//
#include <hip/hip_runtime.h>
#include <hip/hip_bf16.h>

#define IN_C 512
#define OUT_C 256
#define NN 8192
#define MASK_BYTES (NN * (NN / 8))   // 8 MiB

typedef __attribute__((ext_vector_type(8))) short s16x8;
typedef __attribute__((ext_vector_type(4))) float f32x4;

__device__ __forceinline__ ushort f2bf(float f) {
    unsigned u = __float_as_uint(f);
    unsigned r = (u + 0x7FFF + ((u >> 16) & 1)) >> 16;
    return (ushort)r;
}

// ---------------- Kernel P: pack adj (int32 0/1) -> bitmask, 1 bit per edge ----------------
// byte b covers adj[b*8 .. b*8+7], bit e = adj[b*8+e] > 0  (LSB-first)
__global__ __launch_bounds__(256) void pack_kernel(const int* __restrict__ adj,
                                                   unsigned char* __restrict__ mask)
{
    const size_t stride = (size_t)gridDim.x * 256;
    for (size_t b = (size_t)blockIdx.x * 256 + threadIdx.x; b < (size_t)MASK_BYTES; b += stride) {
        const int4 a = ((const int4*)adj)[b * 2];
        const int4 c = ((const int4*)adj)[b * 2 + 1];
        unsigned v = (unsigned)(a.x > 0)
                   | ((unsigned)(a.y > 0) << 1)
                   | ((unsigned)(a.z > 0) << 2)
                   | ((unsigned)(a.w > 0) << 3)
                   | ((unsigned)(c.x > 0) << 4)
                   | ((unsigned)(c.y > 0) << 5)
                   | ((unsigned)(c.z > 0) << 6)
                   | ((unsigned)(c.w > 0) << 7);
        mask[b] = (unsigned char)v;
    }
}

// ---------------- Kernel A: h = x@W_fc + b_fc (fp32), h_t (bf16, transposed), s1, s2 ----------------
__global__ __launch_bounds__(256) void fc_kernel(
    const float* __restrict__ x, const float* __restrict__ Wfc,
    const float* __restrict__ bfc, const float* __restrict__ Wa1,
    const float* __restrict__ ba1, const float* __restrict__ Wa2,
    const float* __restrict__ ba2,
    ushort* __restrict__ h_t,   // [OUT_C][NN] bf16
    float* __restrict__ s1, float* __restrict__ s2)
{
    __shared__ float xl[8 * IN_C];          // 16 KB
    __shared__ float red[2][8][4];
    const int t = threadIdx.x;
    const int r0 = blockIdx.x * 8;

    {
        const float4* src = (const float4*)(x + (size_t)r0 * IN_C);
        float4* dst = (float4*)xl;
        #pragma unroll
        for (int i = 0; i < 4; i++) dst[i * 256 + t] = src[i * 256 + t];
    }
    __syncthreads();

    float acc[8];
    #pragma unroll
    for (int r = 0; r < 8; r++) acc[r] = 0.f;

    for (int c4 = 0; c4 < IN_C / 4; c4++) {
        const float w0 = Wfc[(c4 * 4 + 0) * OUT_C + t];
        const float w1 = Wfc[(c4 * 4 + 1) * OUT_C + t];
        const float w2 = Wfc[(c4 * 4 + 2) * OUT_C + t];
        const float w3 = Wfc[(c4 * 4 + 3) * OUT_C + t];
        #pragma unroll
        for (int r = 0; r < 8; r++) {
            const float4 xv = *(const float4*)&xl[r * IN_C + c4 * 4];
            acc[r] = fmaf(xv.x, w0, acc[r]);
            acc[r] = fmaf(xv.y, w1, acc[r]);
            acc[r] = fmaf(xv.z, w2, acc[r]);
            acc[r] = fmaf(xv.w, w3, acc[r]);
        }
    }
    const float bb = bfc[t];
    #pragma unroll
    for (int r = 0; r < 8; r++) acc[r] += bb;

    {
        union { ushort u[8]; uint4 v; } pk;
        #pragma unroll
        for (int r = 0; r < 8; r++) pk.u[r] = f2bf(acc[r]);
        *(uint4*)(h_t + (size_t)t * NN + r0) = pk.v;
    }

    float p1[8], p2[8];
    const float wa1 = Wa1[t], wa2 = Wa2[t];
    #pragma unroll
    for (int r = 0; r < 8; r++) { p1[r] = acc[r] * wa1; p2[r] = acc[r] * wa2; }
    #pragma unroll
    for (int off = 32; off > 0; off >>= 1) {
        #pragma unroll
        for (int r = 0; r < 8; r++) {
            p1[r] += __shfl_down(p1[r], off);
            p2[r] += __shfl_down(p2[r], off);
        }
    }
    const int wv = t >> 6, ln = t & 63;
    if (ln == 0) {
        #pragma unroll
        for (int r = 0; r < 8; r++) { red[0][r][wv] = p1[r]; red[1][r][wv] = p2[r]; }
    }
    __syncthreads();
    if (t < 16) {
        const int s = t >> 3, r = t & 7;
        float v = red[s][r][0] + red[s][r][1] + red[s][r][2] + red[s][r][3];
        v += s ? ba2[0] : ba1[0];
        if (s) s2[r0 + r] = v; else s1[r0 + r] = v;
    }
}

// ---------------- Kernel A2: smax = max(s2) ----------------
__global__ __launch_bounds__(256) void smax_kernel(const float* __restrict__ s2,
                                                   float* __restrict__ smax)
{
    __shared__ float red[4];
    float m = -1e30f;
    for (int i = threadIdx.x; i < NN; i += 256) m = fmaxf(m, s2[i]);
    #pragma unroll
    for (int off = 32; off > 0; off >>= 1) m = fmaxf(m, __shfl_down(m, off));
    if ((threadIdx.x & 63) == 0) red[threadIdx.x >> 6] = m;
    __syncthreads();
    if (threadIdx.x == 0)
        smax[0] = fmaxf(fmaxf(red[0], red[1]), fmaxf(red[2], red[3]));
}

// ---------------- Kernel B: masked softmax-numerator @ h (bf16 MFMA), partials ----------------
#define JSPL 4
#define JRANGE (NN / JSPL)   // 2048

__global__ __launch_bounds__(256) void attn_kernel(
    const unsigned long long* __restrict__ mask, const ushort* __restrict__ h_t,
    const float* __restrict__ s1, const float* __restrict__ s2,
    const float* __restrict__ smaxp, float* __restrict__ outp,
    float* __restrict__ pbase, float* __restrict__ rs)
{
    __shared__ float s2l[JRANGE];           // 8 KB
    __shared__ uint4 hl4[256][8];           // 32 KB, [col][16B-chunk], XOR-swizzled

    const int t = threadIdx.x;
    const int wave = t >> 6, lane = t & 63;
    const int g = lane >> 4, lr = lane & 15;
    const int jq = blockIdx.y;
    const int Jbase = jq * JRANGE;
    const int row = blockIdx.x * 64 + wave * 16 + lr;

    // stage this block's s2 slice
    {
        const float4* src = (const float4*)(s2 + Jbase);
        float4* dst = (float4*)s2l;
        #pragma unroll
        for (int i = 0; i < JRANGE / 4 / 256; i++) dst[i * 256 + t] = src[i * 256 + t];
    }

    const float my_s1 = s1[row];
    const float smax = smaxp[0];
    const float z0 = my_s1 + smax;
    const float m_i = fmaxf(z0, 0.01f * z0);   // upper bound of masked row max

    f32x4 acc[16];
    #pragma unroll
    for (int n = 0; n < 16; n++) acc[n] = (f32x4)(0.f);
    float rsum = 0.f;

    const unsigned long long* mrow = mask + (size_t)row * (NN / 64) + (Jbase >> 6);
    const ushort* hsrc = h_t + (size_t)t * NN + Jbase;
    const int tswz = t & 7;
    const int csw = lr & 7;

    // prologue: stage tile J=0
    {
        const uint4* src = (const uint4*)hsrc;
        #pragma unroll
        for (int u = 0; u < 8; u++) hl4[t][u ^ tswz] = src[u];
    }
    __syncthreads();

    for (int J = 0; J < JRANGE; J += 64) {
        // T14: issue next tile's global loads early (L2-resident h_t)
        uint4 pre[8];
        const bool more = (J + 64 < JRANGE);
        if (more) {
            const uint4* src = (const uint4*)(hsrc + J + 64);
            #pragma unroll
            for (int u = 0; u < 8; u++) pre[u] = src[u];
        }
        const unsigned long long m64 = mrow[J >> 6];

        #pragma unroll
        for (int s = 0; s < 2; s++) {
            const int kl = s * 32 + g * 8;
            const int j0 = J + kl;
            const unsigned mb = (unsigned)(m64 >> kl) & 0xFFu;
            const float4 sva = *(const float4*)(s2l + j0);
            const float4 svb = *(const float4*)(s2l + j0 + 4);
            const float sv[8] = {sva.x, sva.y, sva.z, sva.w, svb.x, svb.y, svb.z, svb.w};
            union { ushort u[8]; s16x8 v; } pk;
            #pragma unroll
            for (int e = 0; e < 8; e++) {
                const float zz = my_s1 + sv[e];
                const float ee = fmaxf(zz, 0.01f * zz);   // leaky_relu
                float p = __expf(ee - m_i);
                p = ((mb >> e) & 1u) ? p : 0.f;
                rsum += p;
                pk.u[e] = f2bf(p);
            }
            const s16x8 afrag = pk.v;
            const int slot = (s * 4 + g) ^ csw;
            #pragma unroll
            for (int n = 0; n < 16; n++) {
                const int col = n * 16 + lr;
                const s16x8 bfrag = *(const s16x8*)&hl4[col][slot];
                acc[n] = __builtin_amdgcn_mfma_f32_16x16x32_bf16(afrag, bfrag, acc[n], 0, 0, 0);
            }
        }
        __syncthreads();
        if (more) {
            #pragma unroll
            for (int u = 0; u < 8; u++) hl4[t][u ^ tswz] = pre[u];
        }
        __syncthreads();
    }

    // full row-sum: reduce across the 4 k-groups
    rsum += __shfl_xor(rsum, 16);
    rsum += __shfl_xor(rsum, 32);
    if (g == 0) rs[(size_t)jq * NN + row] = rsum;

    float* dst = (jq == 0) ? outp : (pbase + (size_t)(jq - 1) * ((size_t)NN * OUT_C));
    #pragma unroll
    for (int r = 0; r < 4; r++) {
        const int orow = blockIdx.x * 64 + wave * 16 + g * 4 + r;
        float* op = dst + (size_t)orow * OUT_C + lr;
        #pragma unroll
        for (int n = 0; n < 16; n++) op[n * 16] = acc[n][r];
    }
}

// ---------------- Kernel C: combine partials, normalize ----------------
__global__ __launch_bounds__(256) void combine_kernel(
    float* __restrict__ out, const float* __restrict__ pbase,
    const float* __restrict__ rs)
{
    const int row = blockIdx.x, t = threadIdx.x;
    const float rsum = rs[row] + rs[NN + row] + rs[2 * NN + row] + rs[3 * NN + row];
    const float inv = 1.f / rsum;
    const size_t idx = (size_t)row * OUT_C + t;
    const size_t stride = (size_t)NN * OUT_C;
    const float v = out[idx] + pbase[idx] + pbase[idx + stride] + pbase[idx + 2 * stride];
    out[idx] = v * inv;
}

extern "C" void kernel_launch(void* const* d_in, const int* in_sizes, int n_in,
                              void* d_out, int out_size, void* d_ws, size_t ws_size,
                              hipStream_t stream) {
    const float* x   = (const float*)d_in[0];
    const int*   adj = (const int*)d_in[1];
    const float* Wfc = (const float*)d_in[2];
    const float* bfc = (const float*)d_in[3];
    const float* Wa1 = (const float*)d_in[4];
    const float* ba1 = (const float*)d_in[5];
    const float* Wa2 = (const float*)d_in[6];
    const float* ba2 = (const float*)d_in[7];
    float* out = (float*)d_out;

    char* ws = (char*)d_ws;
    ushort* h_t = (ushort*)ws;                       // 4 MiB   [256][8192] bf16
    float* s1   = (float*)(ws + (4u << 20));         // 32 KiB
    float* s2   = s1 + NN;                           // 32 KiB
    float* rs   = s2 + NN;                           // 128 KiB [4][8192]
    float* smax = rs + 4 * NN;                       // 4 B
    float* pbase = (float*)(ws + (5u << 20));        // 24 MiB  [3][8192][256] f32
    unsigned char* mask = (unsigned char*)(ws + (29u << 20));  // 8 MiB bitmask

    pack_kernel<<<dim3(2048), 256, 0, stream>>>(adj, mask);
    fc_kernel<<<dim3(NN / 8), 256, 0, stream>>>(x, Wfc, bfc, Wa1, ba1, Wa2, ba2, h_t, s1, s2);
    smax_kernel<<<dim3(1), 256, 0, stream>>>(s2, smax);
    attn_kernel<<<dim3(NN / 64, JSPL), 256, 0, stream>>>((const unsigned long long*)mask,
                                                         h_t, s1, s2, smax, out, pbase, rs);
    combine_kernel<<<dim3(NN), 256, 0, stream>>>(out, pbase, rs);
}

// Round 3
// 179.963 us; speedup vs baseline: 1.7221x; 1.7221x over previous
//
#include <hip/hip_runtime.h>
#include <hip/hip_bf16.h>

#define IN_C 512
#define OUT_C 256
#define NN 8192
#define JSPL 4
#define JRANGE (NN / JSPL)   // 2048
#define NT (JRANGE / 64)     // 32 tiles per block

typedef __attribute__((ext_vector_type(8))) short s16x8;
typedef __attribute__((ext_vector_type(4))) float f32x4;

__device__ __forceinline__ ushort f2bf(float f) {
    unsigned u = __float_as_uint(f);
    unsigned r = (u + 0x7FFF + ((u >> 16) & 1)) >> 16;
    return (ushort)r;
}

__device__ __forceinline__ void gload_lds16(const uint4* g, uint4* l) {
    __builtin_amdgcn_global_load_lds(
        (const __attribute__((address_space(1))) unsigned int*)g,
        (__attribute__((address_space(3))) unsigned int*)l, 16, 0, 0);
}

// ---------------- Kernel A: h = x@W_fc + b_fc (fp32); store h in tile-blocked,
// pre-swizzled bf16 layout hb[jt][col][u ^ (col&7)] (uint4 = 8 bf16 of k);
// also s1 = h@Wa1+ba1, s2 = h@Wa2+ba2 ----------------
__global__ __launch_bounds__(256) void fc_kernel(
    const float* __restrict__ x, const float* __restrict__ Wfc,
    const float* __restrict__ bfc, const float* __restrict__ Wa1,
    const float* __restrict__ ba1, const float* __restrict__ Wa2,
    const float* __restrict__ ba2,
    uint4* __restrict__ hb,     // [NN/64][256][8] uint4
    float* __restrict__ s1, float* __restrict__ s2)
{
    __shared__ float xl[8 * IN_C];          // 16 KB
    __shared__ float red[2][8][4];
    const int t = threadIdx.x;
    const int r0 = blockIdx.x * 8;

    {
        const float4* src = (const float4*)(x + (size_t)r0 * IN_C);
        float4* dst = (float4*)xl;
        #pragma unroll
        for (int i = 0; i < 4; i++) dst[i * 256 + t] = src[i * 256 + t];
    }
    __syncthreads();

    float acc[8];
    #pragma unroll
    for (int r = 0; r < 8; r++) acc[r] = 0.f;

    for (int c4 = 0; c4 < IN_C / 4; c4++) {
        const float w0 = Wfc[(c4 * 4 + 0) * OUT_C + t];
        const float w1 = Wfc[(c4 * 4 + 1) * OUT_C + t];
        const float w2 = Wfc[(c4 * 4 + 2) * OUT_C + t];
        const float w3 = Wfc[(c4 * 4 + 3) * OUT_C + t];
        #pragma unroll
        for (int r = 0; r < 8; r++) {
            const float4 xv = *(const float4*)&xl[r * IN_C + c4 * 4];
            acc[r] = fmaf(xv.x, w0, acc[r]);
            acc[r] = fmaf(xv.y, w1, acc[r]);
            acc[r] = fmaf(xv.z, w2, acc[r]);
            acc[r] = fmaf(xv.w, w3, acc[r]);
        }
    }
    const float bb = bfc[t];
    #pragma unroll
    for (int r = 0; r < 8; r++) acc[r] += bb;

    // store: rows r0..r0+7 are k-chunk u=(r0>>3)&7 of tile jt=r0>>6, col=t
    {
        union { ushort u[8]; uint4 v; } pk;
        #pragma unroll
        for (int r = 0; r < 8; r++) pk.u[r] = f2bf(acc[r]);
        const int jt = r0 >> 6, u = (r0 >> 3) & 7;
        hb[(size_t)jt * 2048 + t * 8 + (u ^ (t & 7))] = pk.v;
    }

    float p1[8], p2[8];
    const float wa1 = Wa1[t], wa2 = Wa2[t];
    #pragma unroll
    for (int r = 0; r < 8; r++) { p1[r] = acc[r] * wa1; p2[r] = acc[r] * wa2; }
    #pragma unroll
    for (int off = 32; off > 0; off >>= 1) {
        #pragma unroll
        for (int r = 0; r < 8; r++) {
            p1[r] += __shfl_down(p1[r], off);
            p2[r] += __shfl_down(p2[r], off);
        }
    }
    const int wv = t >> 6, ln = t & 63;
    if (ln == 0) {
        #pragma unroll
        for (int r = 0; r < 8; r++) { red[0][r][wv] = p1[r]; red[1][r][wv] = p2[r]; }
    }
    __syncthreads();
    if (t < 16) {
        const int s = t >> 3, r = t & 7;
        float v = red[s][r][0] + red[s][r][1] + red[s][r][2] + red[s][r][3];
        v += s ? ba2[0] : ba1[0];
        if (s) s2[r0 + r] = v; else s1[r0 + r] = v;
    }
}

// ---------------- Kernel A2: smax = max(s2) ----------------
__global__ __launch_bounds__(256) void smax_kernel(const float* __restrict__ s2,
                                                   float* __restrict__ smax)
{
    __shared__ float red[4];
    float m = -1e30f;
    for (int i = threadIdx.x; i < NN; i += 256) m = fmaxf(m, s2[i]);
    #pragma unroll
    for (int off = 32; off > 0; off >>= 1) m = fmaxf(m, __shfl_down(m, off));
    if ((threadIdx.x & 63) == 0) red[threadIdx.x >> 6] = m;
    __syncthreads();
    if (threadIdx.x == 0)
        smax[0] = fmaxf(fmaxf(red[0], red[1]), fmaxf(red[2], red[3]));
}

// ---------------- Kernel B: masked softmax-numerator @ h (bf16 MFMA) ----------------
// grid (128, 4): 64 rows/block (4 waves x 16 rows), J-quarter per blockIdx.y.
// T3-minimum pipeline: stage(next tile via global_load_lds) -> compute(cur) ->
// __syncthreads (drains vmcnt) -> swap. adj prefetched 1 tile ahead in 16 VGPRs.
__global__ __launch_bounds__(256, 2) void attn_kernel(
    const int* __restrict__ adj, const uint4* __restrict__ hb,
    const float* __restrict__ s1, const float* __restrict__ s2,
    const float* __restrict__ smaxp, float* __restrict__ outp,
    float* __restrict__ pbase, float* __restrict__ rs)
{
    __shared__ float s2l[JRANGE];           // 8 KB
    __shared__ uint4 hbuf[2][2048];         // 64 KB double-buffered h tile

    const int t = threadIdx.x;
    const int wave = t >> 6, lane = t & 63;
    const int g = lane >> 4, lr = lane & 15;
    const int jq = blockIdx.y;
    const int Jbase = jq * JRANGE;
    const int row = blockIdx.x * 64 + wave * 16 + lr;

    // stage s2 slice
    {
        const float4* src = (const float4*)(s2 + Jbase);
        float4* dst = (float4*)s2l;
        #pragma unroll
        for (int i = 0; i < JRANGE / 4 / 256; i++) dst[i * 256 + t] = src[i * 256 + t];
    }

    const float my_s1 = s1[row];
    const float z0 = my_s1 + smaxp[0];
    const float m_i = fmaxf(z0, 0.01f * z0);   // upper bound of masked row max

    f32x4 acc[16];
    #pragma unroll
    for (int n = 0; n < 16; n++) acc[n] = (f32x4)(0.f);
    float rsum = 0.f;

    const int* adj_row = adj + (size_t)row * NN + Jbase + g * 8;
    const uint4* hb_base = hb + (size_t)(Jbase >> 6) * 2048;
    const int stidx = wave * 512 + lane;    // uint4 index; +u*64 per chunk

    // prologue: stage tile 0 (DMA) + adj tile 0 (regs)
    #pragma unroll
    for (int u = 0; u < 8; u++)
        gload_lds16(hb_base + stidx + u * 64, &hbuf[0][stidx + u * 64]);
    int4 ap0 = *(const int4*)(adj_row);
    int4 ap1 = *(const int4*)(adj_row + 4);
    int4 ap2 = *(const int4*)(adj_row + 32);
    int4 ap3 = *(const int4*)(adj_row + 36);
    __syncthreads();

    for (int tt = 0; tt < NT; ++tt) {
        const int cur = tt & 1;
        const bool more = (tt + 1 < NT);
        // stage next h tile into other buffer (nobody reads it this iter)
        if (more) {
            const uint4* gs = hb_base + (size_t)(tt + 1) * 2048 + stidx;
            #pragma unroll
            for (int u = 0; u < 8; u++)
                gload_lds16(gs + u * 64, &hbuf[cur ^ 1][stidx + u * 64]);
        }
        // move adj tile to use-regs, issue next tile's adj loads
        const int av[16] = {ap0.x, ap0.y, ap0.z, ap0.w, ap1.x, ap1.y, ap1.z, ap1.w,
                            ap2.x, ap2.y, ap2.z, ap2.w, ap3.x, ap3.y, ap3.z, ap3.w};
        if (more) {
            const int* anx = adj_row + (tt + 1) * 64;
            ap0 = *(const int4*)(anx);
            ap1 = *(const int4*)(anx + 4);
            ap2 = *(const int4*)(anx + 32);
            ap3 = *(const int4*)(anx + 36);
        }

        const int J = tt * 64;
        #pragma unroll
        for (int s = 0; s < 2; s++) {
            const int j0 = J + s * 32 + g * 8;
            const float4 sva = *(const float4*)(s2l + j0);
            const float4 svb = *(const float4*)(s2l + j0 + 4);
            const float sv[8] = {sva.x, sva.y, sva.z, sva.w, svb.x, svb.y, svb.z, svb.w};
            union { ushort u[8]; s16x8 v; } pk;
            #pragma unroll
            for (int e = 0; e < 8; e++) {
                const float zz = my_s1 + sv[e];
                const float ee = fmaxf(zz, 0.01f * zz);   // leaky_relu
                float p = __expf(ee - m_i);
                p = (av[s * 8 + e] > 0) ? p : 0.f;
                rsum += p;
                pk.u[e] = f2bf(p);
            }
            const s16x8 afrag = pk.v;
            const int slot = (s * 4 + g) ^ (lr & 7);
            #pragma unroll
            for (int n = 0; n < 16; n++) {
                const int col = n * 16 + lr;
                const s16x8 bfrag = *(const s16x8*)&hbuf[cur][col * 8 + slot];
                acc[n] = __builtin_amdgcn_mfma_f32_16x16x32_bf16(afrag, bfrag, acc[n], 0, 0, 0);
            }
        }
        __syncthreads();   // compiler drains vmcnt(0): stage(tt+1) complete, buf free
    }

    // row-sum reduce across the 4 k-groups
    rsum += __shfl_xor(rsum, 16);
    rsum += __shfl_xor(rsum, 32);
    if (g == 0) rs[(size_t)jq * NN + row] = rsum;

    float* dst = (jq == 0) ? outp : (pbase + (size_t)(jq - 1) * ((size_t)NN * OUT_C));
    #pragma unroll
    for (int r = 0; r < 4; r++) {
        const int orow = blockIdx.x * 64 + wave * 16 + g * 4 + r;
        float* op = dst + (size_t)orow * OUT_C + lr;
        #pragma unroll
        for (int n = 0; n < 16; n++) op[n * 16] = acc[n][r];
    }
}

// ---------------- Kernel C: combine partials, normalize ----------------
__global__ __launch_bounds__(256) void combine_kernel(
    float* __restrict__ out, const float* __restrict__ pbase,
    const float* __restrict__ rs)
{
    const int row = blockIdx.x, t = threadIdx.x;
    const float rsum = rs[row] + rs[NN + row] + rs[2 * NN + row] + rs[3 * NN + row];
    const float inv = 1.f / rsum;
    const size_t idx = (size_t)row * OUT_C + t;
    const size_t stride = (size_t)NN * OUT_C;
    const float v = out[idx] + pbase[idx] + pbase[idx + stride] + pbase[idx + 2 * stride];
    out[idx] = v * inv;
}

extern "C" void kernel_launch(void* const* d_in, const int* in_sizes, int n_in,
                              void* d_out, int out_size, void* d_ws, size_t ws_size,
                              hipStream_t stream) {
    const float* x   = (const float*)d_in[0];
    const int*   adj = (const int*)d_in[1];
    const float* Wfc = (const float*)d_in[2];
    const float* bfc = (const float*)d_in[3];
    const float* Wa1 = (const float*)d_in[4];
    const float* ba1 = (const float*)d_in[5];
    const float* Wa2 = (const float*)d_in[6];
    const float* ba2 = (const float*)d_in[7];
    float* out = (float*)d_out;

    char* ws = (char*)d_ws;
    uint4* hb   = (uint4*)ws;                        // 4 MiB   [128][256][8] uint4
    float* s1   = (float*)(ws + (4u << 20));         // 32 KiB
    float* s2   = s1 + NN;                           // 32 KiB
    float* rs   = s2 + NN;                           // 128 KiB [4][8192]
    float* smax = rs + 4 * NN;                       // 4 B
    float* pbase = (float*)(ws + (5u << 20));        // 24 MiB  [3][8192][256] f32

    fc_kernel<<<dim3(NN / 8), 256, 0, stream>>>(x, Wfc, bfc, Wa1, ba1, Wa2, ba2, hb, s1, s2);
    smax_kernel<<<dim3(1), 256, 0, stream>>>(s2, smax);
    attn_kernel<<<dim3(NN / 64, JSPL), 256, 0, stream>>>(adj, hb, s1, s2, smax, out, pbase, rs);
    combine_kernel<<<dim3(NN), 256, 0, stream>>>(out, pbase, rs);
}